// Round 7
// baseline (163.334 us; speedup 1.0000x reference)
//
#include <hip/hip_runtime.h>

#define N_NODES 20000
#define N_EDGES 640000
#define N_GRAPHS 64

// pool tiling
#define NCHUNK 128
#define CHUNK_SZ 157   // 128*157 = 20096 >= 20000
#define GSPLIT 8       // graph-dim split: 8 blocks of 8 graphs each
#define GSUB 8

// graph-bucket sort (fixed per-(block,g) segments; no cursor, no memset)
#define BG_TILE 2048
#define NBG 313        // ceil(640000/2048)
#define SEGCAP 80      // per-(block,g) slots: mean ~32-39, sigma ~6 -> >6.6 sigma
#define GR_CAP 768     // max nodes per graph: mean 312.5, sigma 17.5 -> 26 sigma

// ws layout (4B units), ws_size = 256 MiB:
//   Cdcol  [64][20000] f32     at 0          (1,280,000) per-graph dst-count column
//   deg    [20000] f32         at 1,280,000  (dense per-range writes by cd_col_k)
//   counts [64] f32            at 1,300,000  (dense writes by cd_col_k q==0)
//   Y      [64][256] f32       at 1,300,064  (zeroed by bucket_g_k blk0; pool atomics)
//   part   [128][64][256] f32  at 1,316,448  (2,097,152)
//   bh     [313][64] u32       at 3,413,600  (20,032)
//   vals   [64][313][80] u32   at 3,433,632  (1,602,560)
// end = 5,036,192 words = 20.1 MB << 256 MiB
#define CD_OFF      0
#define DEG_OFF     1280000
#define CNT_OFF     1300000
#define Y_OFF       1300064
#define PART_OFF    1316448
#define BH_OFF      3413600
#define VALS_OFF    3433632

// bucket edges by g = batch[src]: LDS rank, fixed segment per (g,block),
// packed val = (src<<15)|dst (both < 2^15). Dense block-hist out; no atomics
// beyond LDS. Block 0 zeroes Y.
__global__ __launch_bounds__(256) void bucket_g_k(const int* __restrict__ ei,
                                                  const int* __restrict__ batch,
                                                  unsigned* __restrict__ vals,
                                                  unsigned* __restrict__ bh,
                                                  float* __restrict__ Y) {
    __shared__ unsigned hist[N_GRAPHS];
    const int t = threadIdx.x;
    const int blk = blockIdx.x;
    if (t < N_GRAPHS) hist[t] = 0u;
    __syncthreads();

    const int e0 = blk * BG_TILE;
    unsigned pv[8], rnk[8], gg[8];
#pragma unroll
    for (int k = 0; k < 8; ++k) {
        int e = e0 + t + k * 256;
        if (e < N_EDGES) {
            unsigned s = (unsigned)ei[e];
            unsigned d = (unsigned)ei[N_EDGES + e];
            unsigned g = (unsigned)batch[s];
            pv[k] = (s << 15) | d;
            gg[k] = g;
            rnk[k] = atomicAdd(&hist[g], 1u);
        } else {
            gg[k] = 0xFFFFFFFFu;
        }
    }
#pragma unroll
    for (int k = 0; k < 8; ++k) {
        unsigned g = gg[k];
        if (g != 0xFFFFFFFFu && rnk[k] < SEGCAP)
            vals[((size_t)g * NBG + blk) * SEGCAP + rnk[k]] = pv[k];
    }
    __syncthreads();
    if (t < N_GRAPHS) {
        unsigned c = hist[t];
        bh[blk * N_GRAPHS + t] = (c > SEGCAP) ? SEGCAP : c;
    }
    if (blk == 0) {   // zero pool's atomic target (replaces memset dispatch)
        float4* y4 = (float4*)Y;
        for (int i = t; i < 64 * 64; i += 256) y4[i] = make_float4(0.f, 0.f, 0.f, 0.f);
    }
}

// block = (g, quarter): replay bucket g's segments, dst-hist for quarter of the
// node range (u16-packed, 10 KB); q==0 also builds deg over g's contiguous
// node range (3 KB) + counts[g]. Dense writes only.
__global__ __launch_bounds__(256) void cd_col_k(const unsigned* __restrict__ vals,
                                                const unsigned* __restrict__ bh,
                                                const int* __restrict__ batch,
                                                float* __restrict__ Cdcol,
                                                float* __restrict__ deg,
                                                float* __restrict__ counts) {
    __shared__ unsigned scnt[NBG];
    __shared__ unsigned dh[2500];       // 5000 dst nodes, u16 halves
    __shared__ unsigned sdeg[GR_CAP];
    __shared__ int s_lo, s_hi;
    __shared__ unsigned s_tot;
    const int t = threadIdx.x;
    const int g = blockIdx.x >> 2;
    const int q = blockIdx.x & 3;
    const int d0 = q * 5000;

    for (int i = t; i < NBG; i += 256) scnt[i] = bh[i * N_GRAPHS + g];
    for (int i = t; i < 2500; i += 256) dh[i] = 0u;
    if (q == 0) {
        for (int i = t; i < GR_CAP; i += 256) sdeg[i] = 0u;
        if (t == 0) {
            int lo = 0, hi = N_NODES;                    // lower_bound(g)
            while (lo < hi) { int m = (lo + hi) >> 1; if (batch[m] < g) lo = m + 1; else hi = m; }
            s_lo = lo;
            int lo2 = lo; hi = N_NODES;                  // lower_bound(g+1)
            while (lo2 < hi) { int m = (lo2 + hi) >> 1; if (batch[m] < g + 1) lo2 = m + 1; else hi = m; }
            s_hi = lo2;
        }
    }
    __syncthreads();
    const int lo = s_lo;

    const unsigned* vg = vals + (size_t)g * NBG * SEGCAP;
    for (int idx = t; idx < NBG * SEGCAP; idx += 256) {
        unsigned blk = (unsigned)idx / SEGCAP;
        unsigned slot = (unsigned)idx - blk * SEGCAP;
        if (slot < scnt[blk]) {
            unsigned v = vg[idx];
            int d = (int)(v & 0x7FFFu);
            int rd = d - d0;
            if ((unsigned)rd < 5000u)
                atomicAdd(&dh[rd >> 1], 1u << ((rd & 1) * 16));
            if (q == 0) {
                int rs = (int)(v >> 15) - lo;
                if ((unsigned)rs < (unsigned)GR_CAP) atomicAdd(&sdeg[rs], 1u);
            }
        }
    }
    __syncthreads();

    float2* outc = (float2*)(Cdcol + (size_t)g * N_NODES + d0);
    for (int w = t; w < 2500; w += 256) {
        unsigned v = dh[w];
        outc[w] = make_float2((float)(v & 0xFFFFu), (float)(v >> 16));
    }
    if (q == 0) {
        const int range = s_hi - lo;
        for (int i = t; i < range; i += 256) deg[lo + i] = (float)sdeg[i];
        if (t == 0) {
            unsigned tot = 0;
            for (int i = 0; i < NBG; ++i) tot += scnt[i];
            counts[g] = (float)tot;
        }
    }
}

#define FMA8(C0, C1, XV)                                          \
    acc[0].x = fmaf(C0.x, XV.x, acc[0].x); acc[0].y = fmaf(C0.x, XV.y, acc[0].y); \
    acc[0].z = fmaf(C0.x, XV.z, acc[0].z); acc[0].w = fmaf(C0.x, XV.w, acc[0].w); \
    acc[1].x = fmaf(C0.y, XV.x, acc[1].x); acc[1].y = fmaf(C0.y, XV.y, acc[1].y); \
    acc[1].z = fmaf(C0.y, XV.z, acc[1].z); acc[1].w = fmaf(C0.y, XV.w, acc[1].w); \
    acc[2].x = fmaf(C0.z, XV.x, acc[2].x); acc[2].y = fmaf(C0.z, XV.y, acc[2].y); \
    acc[2].z = fmaf(C0.z, XV.z, acc[2].z); acc[2].w = fmaf(C0.z, XV.w, acc[2].w); \
    acc[3].x = fmaf(C0.w, XV.x, acc[3].x); acc[3].y = fmaf(C0.w, XV.y, acc[3].y); \
    acc[3].z = fmaf(C0.w, XV.z, acc[3].z); acc[3].w = fmaf(C0.w, XV.w, acc[3].w); \
    acc[4].x = fmaf(C1.x, XV.x, acc[4].x); acc[4].y = fmaf(C1.x, XV.y, acc[4].y); \
    acc[4].z = fmaf(C1.x, XV.z, acc[4].z); acc[4].w = fmaf(C1.x, XV.w, acc[4].w); \
    acc[5].x = fmaf(C1.y, XV.x, acc[5].x); acc[5].y = fmaf(C1.y, XV.y, acc[5].y); \
    acc[5].z = fmaf(C1.y, XV.z, acc[5].z); acc[5].w = fmaf(C1.y, XV.w, acc[5].w); \
    acc[6].x = fmaf(C1.z, XV.x, acc[6].x); acc[6].y = fmaf(C1.z, XV.y, acc[6].y); \
    acc[6].z = fmaf(C1.z, XV.z, acc[6].z); acc[6].w = fmaf(C1.z, XV.w, acc[6].w); \
    acc[7].x = fmaf(C1.w, XV.x, acc[7].x); acc[7].y = fmaf(C1.w, XV.y, acc[7].y); \
    acc[7].z = fmaf(C1.w, XV.z, acc[7].z); acc[7].w = fmaf(C1.w, XV.w, acc[7].w);

// pool: block = (chunk b, split j of 8 graphs). 4 waves = 4 node phases,
// x prefetched one iteration ahead, Cd columns transposed into LDS, tree reduce.
__global__ __launch_bounds__(256) void pool_k(const float* __restrict__ x,
                                              const int* __restrict__ batch,
                                              const float* __restrict__ Cdcol,
                                              const float* __restrict__ deg,
                                              float* __restrict__ Y,
                                              float* __restrict__ part) {
    __shared__ float4 sc4[CHUNK_SZ * 2];      // 5 KB: [node][2] float4 (GSUB=8)
    __shared__ float sdeg[CHUNK_SZ];
    __shared__ int   sbatch[CHUNK_SZ];
    __shared__ float4 red[2 * GSUB * 64];     // 16 KB cross-phase reduce

    const int t = threadIdx.x;
    const int fg = t & 63;                    // float4 feature group
    const int p  = t >> 6;                    // phase == wave id
    const int b = blockIdx.x & 127;           // same chunk's 8 splits: same XCD mod 8
    const int j = blockIdx.x >> 7;
    const int n0 = b * CHUNK_SZ;
    const int cnt = (n0 + CHUNK_SZ <= N_NODES) ? CHUNK_SZ : (N_NODES - n0);

    // transpose-stage 8 Cd columns into [node][8] LDS layout
    float* sc = (float*)sc4;
    const float* cbase = Cdcol + (size_t)(j * GSUB) * N_NODES + n0;
#pragma unroll
    for (int k = 0; k < GSUB; ++k)
        for (int i = t; i < cnt; i += 256)
            sc[i * GSUB + k] = cbase[(size_t)k * N_NODES + i];
    if (j == 0) {
        for (int i = t; i < cnt; i += 256) {
            sdeg[i] = deg[n0 + i];
            sbatch[i] = batch[n0 + i];
        }
    }
    __syncthreads();

    const float4* x4 = (const float4*)x;
    float4 acc[GSUB];
#pragma unroll
    for (int k = 0; k < GSUB; ++k) acc[k] = make_float4(0.f, 0.f, 0.f, 0.f);

    if (j == 0) {
        float4 accs = make_float4(0.f, 0.f, 0.f, 0.f);
        int gprev = (p < cnt) ? sbatch[p] : 0;
        int i = p;
        float4 xn = make_float4(0.f, 0.f, 0.f, 0.f);
        if (i < cnt) xn = x4[(size_t)(n0 + i) * 64 + fg];
        for (; i < cnt; i += 4) {
            float4 xv = xn;
            if (i + 4 < cnt) xn = x4[(size_t)(n0 + i + 4) * 64 + fg];
            int g = sbatch[i];                  // wave-uniform
            if (g != gprev) {                   // uniform branch
                float* yr = Y + gprev * 256 + fg * 4;
                atomicAdd(yr + 0, accs.x); atomicAdd(yr + 1, accs.y);
                atomicAdd(yr + 2, accs.z); atomicAdd(yr + 3, accs.w);
                accs = make_float4(0.f, 0.f, 0.f, 0.f);
                gprev = g;
            }
            float dg = sdeg[i];
            accs.x = fmaf(dg, xv.x, accs.x); accs.y = fmaf(dg, xv.y, accs.y);
            accs.z = fmaf(dg, xv.z, accs.z); accs.w = fmaf(dg, xv.w, accs.w);
            float4 c0 = sc4[i * 2], c1 = sc4[i * 2 + 1];
            FMA8(c0, c1, xv)
        }
        if (p < cnt) {
            float* yr = Y + gprev * 256 + fg * 4;
            atomicAdd(yr + 0, accs.x); atomicAdd(yr + 1, accs.y);
            atomicAdd(yr + 2, accs.z); atomicAdd(yr + 3, accs.w);
        }
    } else {
        int i = p;
        float4 xn = make_float4(0.f, 0.f, 0.f, 0.f);
        if (i < cnt) xn = x4[(size_t)(n0 + i) * 64 + fg];
        for (; i < cnt; i += 4) {
            float4 xv = xn;
            if (i + 4 < cnt) xn = x4[(size_t)(n0 + i + 4) * 64 + fg];
            float4 c0 = sc4[i * 2], c1 = sc4[i * 2 + 1];
            FMA8(c0, c1, xv)
        }
    }

    // cross-phase reduce 4 -> 2 -> 1 (lane-consecutive, conflict-free)
    if (p >= 2) {
#pragma unroll
        for (int k = 0; k < GSUB; ++k) red[(p - 2) * (GSUB * 64) + k * 64 + fg] = acc[k];
    }
    __syncthreads();
    if (p < 2) {
#pragma unroll
        for (int k = 0; k < GSUB; ++k) {
            float4 v = red[p * (GSUB * 64) + k * 64 + fg];
            acc[k].x += v.x; acc[k].y += v.y; acc[k].z += v.z; acc[k].w += v.w;
        }
    }
    __syncthreads();
    if (p == 1) {
#pragma unroll
        for (int k = 0; k < GSUB; ++k) red[k * 64 + fg] = acc[k];
    }
    __syncthreads();
    if (p == 0) {
        float4* part4 = (float4*)part;
#pragma unroll
        for (int k = 0; k < GSUB; ++k) {
            float4 v = red[k * 64 + fg];
            acc[k].x += v.x; acc[k].y += v.y; acc[k].z += v.z; acc[k].w += v.w;
            part4[(size_t)(b * 64 + j * GSUB + k) * 64 + fg] = acc[k];
        }
    }
}

// fused reduce + chain: 128 blocks x 256 threads. Dst-row blocks (r>=64)
// reduce their 128 part slabs directly; Y rows 64..127 never materialized.
__global__ __launch_bounds__(256) void chain2_k(const float* __restrict__ Y,
                                                const float* __restrict__ part,
                                                const float* __restrict__ counts,
                                                const float* __restrict__ W0, const float* __restrict__ b0,
                                                const float* __restrict__ W1, const float* __restrict__ b1,
                                                const float* __restrict__ W2, const float* __restrict__ b2,
                                                float* __restrict__ out) {
    __shared__ float m[256];
    __shared__ float h[128];
    const int r = blockIdx.x;
    const int t = threadIdx.x;
    const int g = r & 63;
    const int half = (r >= 64) ? 128 : 0;

    float c = counts[g];
    float inv = 1.0f / fmaxf(c, 1.0f);
    float beta = c * inv;

    if (r < 64) {
        m[t] = Y[r * 256 + t] * inv;
    } else {
        float s = 0.0f;
        for (int bb = 0; bb < NCHUNK; ++bb) s += part[(size_t)(bb * 64 + g) * 256 + t];
        m[t] = s * inv;
    }
    __syncthreads();

    if (t < 128) {
        float s1 = 0.0f;
        for (int k = 0; k < 256; ++k) s1 += m[k] * W0[k * 128 + t];
        s1 += beta * b0[t];
        out[g * 768 + 0 + half + t] = s1;
        h[t] = s1;
    }
    __syncthreads();
    float s2 = 0.0f;
    if (t < 128) {
        for (int k = 0; k < 128; ++k) s2 += h[k] * W1[k * 128 + t];
        s2 += beta * b1[t];
        out[g * 768 + 256 + half + t] = s2;
    }
    __syncthreads();
    if (t < 128) h[t] = s2;
    __syncthreads();
    if (t < 128) {
        float s3 = 0.0f;
        for (int k = 0; k < 128; ++k) s3 += h[k] * W2[k * 128 + t];
        s3 += beta * b2[t];
        out[g * 768 + 512 + half + t] = s3;
    }
}

extern "C" void kernel_launch(void* const* d_in, const int* in_sizes, int n_in,
                              void* d_out, int out_size, void* d_ws, size_t ws_size,
                              hipStream_t stream) {
    const float* x     = (const float*)d_in[0];
    const int*   ei    = (const int*)d_in[1];
    const int*   batch = (const int*)d_in[2];
    const float* W0    = (const float*)d_in[3];
    const float* b0    = (const float*)d_in[4];
    const float* W1    = (const float*)d_in[5];
    const float* b1    = (const float*)d_in[6];
    const float* W2    = (const float*)d_in[7];
    const float* b2    = (const float*)d_in[8];
    float* out = (float*)d_out;

    float*    ws     = (float*)d_ws;
    float*    Cdcol  = ws + CD_OFF;
    float*    deg    = ws + DEG_OFF;
    float*    counts = ws + CNT_OFF;
    float*    Y      = ws + Y_OFF;
    float*    part   = ws + PART_OFF;
    unsigned* bh     = (unsigned*)(ws + BH_OFF);
    unsigned* vals   = (unsigned*)(ws + VALS_OFF);

    bucket_g_k<<<NBG, 256, 0, stream>>>(ei, batch, vals, bh, Y);
    cd_col_k<<<N_GRAPHS * 4, 256, 0, stream>>>(vals, bh, batch, Cdcol, deg, counts);
    pool_k<<<NCHUNK * GSPLIT, 256, 0, stream>>>(x, batch, Cdcol, deg, Y, part);
    chain2_k<<<128, 256, 0, stream>>>(Y, part, counts, W0, b0, W1, b1, W2, b2, out);
}

// Round 8
// 129.399 us; speedup vs baseline: 1.2622x; 1.2622x over previous
//
#include <hip/hip_runtime.h>

#define N_NODES 20000
#define N_EDGES 640000
#define N_GRAPHS 64

// pool tiling
#define NCHUNK 128
#define CHUNK_SZ 157   // 128*157 = 20096 >= 20000
#define GSPLIT 8       // graph-dim split: 8 blocks of 8 graphs each
#define GSUB 8

// graph-bucket sort (fixed per-(block,g) segments; no cursor, no memset)
#define BG_TILE 2048
#define NBG 313        // ceil(640000/2048)
#define SEGCAP 80      // per-(block,g) slots: mean ~32, sigma ~5.7 -> >6.6 sigma (R7-proven)
#define GR_CAP 768     // max nodes per graph: mean 312.5, sigma 17.5 -> 26 sigma
#define NSLOT4 (NBG * SEGCAP / 4)   // 6260 uint4 per graph

// ws layout (4B units), ws_size = 256 MiB:
//   Cdcol  [64][20000] f32     at 0          (1,280,000) per-graph dst-count column
//   deg    [20000] f32         at 1,280,000  (dense per-range writes by cd_col_k)
//   counts [64] f32            at 1,300,000  (dense writes by cd_col_k)
//   Y      [64][256] f32       at 1,300,064  (zeroed by bucket_g_k blk0; pool atomics)
//   part   [128][64][256] f32  at 1,316,448  (2,097,152)
//   bh     [313][64] u32       at 3,413,600  (20,032)
//   vals   [64][313][80] u32   at 3,433,632  (1,602,560)
#define CD_OFF      0
#define DEG_OFF     1280000
#define CNT_OFF     1300000
#define Y_OFF       1300064
#define PART_OFF    1316448
#define BH_OFF      3413600
#define VALS_OFF    3433632

// bucket edges by g = batch[src]: LDS rank, fixed segment per (g,block),
// packed val = (src<<15)|dst (both < 2^15). Dense block-hist out. Blk 0 zeroes Y.
__global__ __launch_bounds__(256) void bucket_g_k(const int* __restrict__ ei,
                                                  const int* __restrict__ batch,
                                                  unsigned* __restrict__ vals,
                                                  unsigned* __restrict__ bh,
                                                  float* __restrict__ Y) {
    __shared__ unsigned hist[N_GRAPHS];
    const int t = threadIdx.x;
    const int blk = blockIdx.x;
    if (t < N_GRAPHS) hist[t] = 0u;
    __syncthreads();

    const int e0 = blk * BG_TILE;
    unsigned pv[8], rnk[8], gg[8];
#pragma unroll
    for (int k = 0; k < 8; ++k) {
        int e = e0 + t + k * 256;
        if (e < N_EDGES) {
            unsigned s = (unsigned)ei[e];
            unsigned d = (unsigned)ei[N_EDGES + e];
            unsigned g = (unsigned)batch[s];
            pv[k] = (s << 15) | d;
            gg[k] = g;
            rnk[k] = atomicAdd(&hist[g], 1u);
        } else {
            gg[k] = 0xFFFFFFFFu;
        }
    }
#pragma unroll
    for (int k = 0; k < 8; ++k) {
        unsigned g = gg[k];
        if (g != 0xFFFFFFFFu && rnk[k] < SEGCAP)
            vals[((size_t)g * NBG + blk) * SEGCAP + rnk[k]] = pv[k];
    }
    __syncthreads();
    if (t < N_GRAPHS) {
        unsigned c = hist[t];
        bh[blk * N_GRAPHS + t] = (c > SEGCAP) ? SEGCAP : c;
    }
    if (blk == 0) {   // zero pool's atomic target (replaces memset dispatch)
        float4* y4 = (float4*)Y;
        for (int i = t; i < 64 * 64; i += 256) y4[i] = make_float4(0.f, 0.f, 0.f, 0.f);
    }
}

// one block per graph, 1024 threads (16 waves): full-column dst hist (u16 LDS),
// vals read as coalesced uint4 (SEGCAP%4==0 -> no straddle; seg via magic-mul).
// Also deg over g's contiguous src range + counts[g]. Dense writes only.
__global__ __launch_bounds__(1024) void cd_col_k(const unsigned* __restrict__ vals,
                                                 const unsigned* __restrict__ bh,
                                                 const int* __restrict__ batch,
                                                 float* __restrict__ Cdcol,
                                                 float* __restrict__ deg,
                                                 float* __restrict__ counts) {
    __shared__ unsigned scnt[NBG];
    __shared__ unsigned dh[N_NODES / 2];   // 40 KB: 20000 dst counts, u16 halves
    __shared__ unsigned sdeg[GR_CAP];      // 3 KB
    __shared__ int s_lo, s_hi;
    __shared__ unsigned stot;
    const int t = threadIdx.x;
    const int g = blockIdx.x;

    for (int i = t; i < N_NODES / 2; i += 1024) dh[i] = 0u;
    if (t < NBG) scnt[t] = bh[t * N_GRAPHS + g];
    if (t < GR_CAP) sdeg[t] = 0u;
    if (t == 0) {
        stot = 0u;
        int lo = 0, hi = N_NODES;                    // lower_bound(g)
        while (lo < hi) { int m = (lo + hi) >> 1; if (batch[m] < g) lo = m + 1; else hi = m; }
        s_lo = lo;
        int lo2 = lo; hi = N_NODES;                  // lower_bound(g+1)
        while (lo2 < hi) { int m = (lo2 + hi) >> 1; if (batch[m] < g + 1) lo2 = m + 1; else hi = m; }
        s_hi = lo2;
    }
    __syncthreads();
    const int lo = s_lo;

    const uint4* v4 = (const uint4*)(vals + (size_t)g * NBG * SEGCAP);
    for (int i = t; i < NSLOT4; i += 1024) {
        uint4 v = *(v4 + i);
        unsigned w = (unsigned)i * 4u;
        unsigned seg = (unsigned)(((unsigned long long)w * 53687092ull) >> 32);  // w/80 exact
        unsigned local = w - seg * 80u;
        unsigned c = scnt[seg];
#define CD_ONE(VX, L)                                                        \
        if ((L) < c) {                                                       \
            unsigned d_ = (VX) & 0x7FFFu;                                    \
            atomicAdd(&dh[d_ >> 1], 1u << ((d_ & 1u) * 16));                 \
            int rs_ = (int)((VX) >> 15) - lo;                                \
            if ((unsigned)rs_ < (unsigned)GR_CAP) atomicAdd(&sdeg[rs_], 1u); \
        }
        CD_ONE(v.x, local + 0u)
        CD_ONE(v.y, local + 1u)
        CD_ONE(v.z, local + 2u)
        CD_ONE(v.w, local + 3u)
#undef CD_ONE
    }
    if (t < NBG && scnt[t]) atomicAdd(&stot, scnt[t]);
    __syncthreads();

    float2* outc = (float2*)(Cdcol + (size_t)g * N_NODES);
    for (int w = t; w < N_NODES / 2; w += 1024) {
        unsigned v = dh[w];
        outc[w] = make_float2((float)(v & 0xFFFFu), (float)(v >> 16));
    }
    const int range = s_hi - lo;
    for (int i = t; i < range; i += 1024) deg[lo + i] = (float)sdeg[i];
    if (t == 0) counts[g] = (float)stot;
}

#define FMA8(C0, C1, XV)                                          \
    acc[0].x = fmaf(C0.x, XV.x, acc[0].x); acc[0].y = fmaf(C0.x, XV.y, acc[0].y); \
    acc[0].z = fmaf(C0.x, XV.z, acc[0].z); acc[0].w = fmaf(C0.x, XV.w, acc[0].w); \
    acc[1].x = fmaf(C0.y, XV.x, acc[1].x); acc[1].y = fmaf(C0.y, XV.y, acc[1].y); \
    acc[1].z = fmaf(C0.y, XV.z, acc[1].z); acc[1].w = fmaf(C0.y, XV.w, acc[1].w); \
    acc[2].x = fmaf(C0.z, XV.x, acc[2].x); acc[2].y = fmaf(C0.z, XV.y, acc[2].y); \
    acc[2].z = fmaf(C0.z, XV.z, acc[2].z); acc[2].w = fmaf(C0.z, XV.w, acc[2].w); \
    acc[3].x = fmaf(C0.w, XV.x, acc[3].x); acc[3].y = fmaf(C0.w, XV.y, acc[3].y); \
    acc[3].z = fmaf(C0.w, XV.z, acc[3].z); acc[3].w = fmaf(C0.w, XV.w, acc[3].w); \
    acc[4].x = fmaf(C1.x, XV.x, acc[4].x); acc[4].y = fmaf(C1.x, XV.y, acc[4].y); \
    acc[4].z = fmaf(C1.x, XV.z, acc[4].z); acc[4].w = fmaf(C1.x, XV.w, acc[4].w); \
    acc[5].x = fmaf(C1.y, XV.x, acc[5].x); acc[5].y = fmaf(C1.y, XV.y, acc[5].y); \
    acc[5].z = fmaf(C1.y, XV.z, acc[5].z); acc[5].w = fmaf(C1.y, XV.w, acc[5].w); \
    acc[6].x = fmaf(C1.z, XV.x, acc[6].x); acc[6].y = fmaf(C1.z, XV.y, acc[6].y); \
    acc[6].z = fmaf(C1.z, XV.z, acc[6].z); acc[6].w = fmaf(C1.z, XV.w, acc[6].w); \
    acc[7].x = fmaf(C1.w, XV.x, acc[7].x); acc[7].y = fmaf(C1.w, XV.y, acc[7].y); \
    acc[7].z = fmaf(C1.w, XV.z, acc[7].z); acc[7].w = fmaf(C1.w, XV.w, acc[7].w);

// pool: block = (chunk b, split j of 8 graphs). 4 waves = 4 node phases,
// x prefetched one iteration ahead, Cd columns transposed into LDS, tree reduce.
__global__ __launch_bounds__(256) void pool_k(const float* __restrict__ x,
                                              const int* __restrict__ batch,
                                              const float* __restrict__ Cdcol,
                                              const float* __restrict__ deg,
                                              float* __restrict__ Y,
                                              float* __restrict__ part) {
    __shared__ float4 sc4[CHUNK_SZ * 2];      // 5 KB: [node][2] float4 (GSUB=8)
    __shared__ float sdeg[CHUNK_SZ];
    __shared__ int   sbatch[CHUNK_SZ];
    __shared__ float4 red[2 * GSUB * 64];     // 16 KB cross-phase reduce

    const int t = threadIdx.x;
    const int fg = t & 63;                    // float4 feature group
    const int p  = t >> 6;                    // phase == wave id
    const int b = blockIdx.x & 127;           // same chunk's 8 splits: same XCD mod 8
    const int j = blockIdx.x >> 7;
    const int n0 = b * CHUNK_SZ;
    const int cnt = (n0 + CHUNK_SZ <= N_NODES) ? CHUNK_SZ : (N_NODES - n0);

    // transpose-stage 8 Cd columns into [node][8] LDS layout
    float* sc = (float*)sc4;
    const float* cbase = Cdcol + (size_t)(j * GSUB) * N_NODES + n0;
#pragma unroll
    for (int k = 0; k < GSUB; ++k)
        for (int i = t; i < cnt; i += 256)
            sc[i * GSUB + k] = cbase[(size_t)k * N_NODES + i];
    if (j == 0) {
        for (int i = t; i < cnt; i += 256) {
            sdeg[i] = deg[n0 + i];
            sbatch[i] = batch[n0 + i];
        }
    }
    __syncthreads();

    const float4* x4 = (const float4*)x;
    float4 acc[GSUB];
#pragma unroll
    for (int k = 0; k < GSUB; ++k) acc[k] = make_float4(0.f, 0.f, 0.f, 0.f);

    if (j == 0) {
        float4 accs = make_float4(0.f, 0.f, 0.f, 0.f);
        int gprev = (p < cnt) ? sbatch[p] : 0;
        int i = p;
        float4 xn = make_float4(0.f, 0.f, 0.f, 0.f);
        if (i < cnt) xn = x4[(size_t)(n0 + i) * 64 + fg];
        for (; i < cnt; i += 4) {
            float4 xv = xn;
            if (i + 4 < cnt) xn = x4[(size_t)(n0 + i + 4) * 64 + fg];
            int g = sbatch[i];                  // wave-uniform
            if (g != gprev) {                   // uniform branch
                float* yr = Y + gprev * 256 + fg * 4;
                atomicAdd(yr + 0, accs.x); atomicAdd(yr + 1, accs.y);
                atomicAdd(yr + 2, accs.z); atomicAdd(yr + 3, accs.w);
                accs = make_float4(0.f, 0.f, 0.f, 0.f);
                gprev = g;
            }
            float dg = sdeg[i];
            accs.x = fmaf(dg, xv.x, accs.x); accs.y = fmaf(dg, xv.y, accs.y);
            accs.z = fmaf(dg, xv.z, accs.z); accs.w = fmaf(dg, xv.w, accs.w);
            float4 c0 = sc4[i * 2], c1 = sc4[i * 2 + 1];
            FMA8(c0, c1, xv)
        }
        if (p < cnt) {
            float* yr = Y + gprev * 256 + fg * 4;
            atomicAdd(yr + 0, accs.x); atomicAdd(yr + 1, accs.y);
            atomicAdd(yr + 2, accs.z); atomicAdd(yr + 3, accs.w);
        }
    } else {
        int i = p;
        float4 xn = make_float4(0.f, 0.f, 0.f, 0.f);
        if (i < cnt) xn = x4[(size_t)(n0 + i) * 64 + fg];
        for (; i < cnt; i += 4) {
            float4 xv = xn;
            if (i + 4 < cnt) xn = x4[(size_t)(n0 + i + 4) * 64 + fg];
            float4 c0 = sc4[i * 2], c1 = sc4[i * 2 + 1];
            FMA8(c0, c1, xv)
        }
    }

    // cross-phase reduce 4 -> 2 -> 1 (lane-consecutive, conflict-free)
    if (p >= 2) {
#pragma unroll
        for (int k = 0; k < GSUB; ++k) red[(p - 2) * (GSUB * 64) + k * 64 + fg] = acc[k];
    }
    __syncthreads();
    if (p < 2) {
#pragma unroll
        for (int k = 0; k < GSUB; ++k) {
            float4 v = red[p * (GSUB * 64) + k * 64 + fg];
            acc[k].x += v.x; acc[k].y += v.y; acc[k].z += v.z; acc[k].w += v.w;
        }
    }
    __syncthreads();
    if (p == 1) {
#pragma unroll
        for (int k = 0; k < GSUB; ++k) red[k * 64 + fg] = acc[k];
    }
    __syncthreads();
    if (p == 0) {
        float4* part4 = (float4*)part;
#pragma unroll
        for (int k = 0; k < GSUB; ++k) {
            float4 v = red[k * 64 + fg];
            acc[k].x += v.x; acc[k].y += v.y; acc[k].z += v.z; acc[k].w += v.w;
            part4[(size_t)(b * 64 + j * GSUB + k) * 64 + fg] = acc[k];
        }
    }
}

// fused reduce + chain: 128 blocks x 256 threads. Dst-row blocks (r>=64)
// reduce their 128 part slabs directly; Y rows 64..127 never materialized.
__global__ __launch_bounds__(256) void chain2_k(const float* __restrict__ Y,
                                                const float* __restrict__ part,
                                                const float* __restrict__ counts,
                                                const float* __restrict__ W0, const float* __restrict__ b0,
                                                const float* __restrict__ W1, const float* __restrict__ b1,
                                                const float* __restrict__ W2, const float* __restrict__ b2,
                                                float* __restrict__ out) {
    __shared__ float m[256];
    __shared__ float h[128];
    const int r = blockIdx.x;
    const int t = threadIdx.x;
    const int g = r & 63;
    const int half = (r >= 64) ? 128 : 0;

    float c = counts[g];
    float inv = 1.0f / fmaxf(c, 1.0f);
    float beta = c * inv;

    if (r < 64) {
        m[t] = Y[r * 256 + t] * inv;
    } else {
        float s = 0.0f;
        for (int bb = 0; bb < NCHUNK; ++bb) s += part[(size_t)(bb * 64 + g) * 256 + t];
        m[t] = s * inv;
    }
    __syncthreads();

    if (t < 128) {
        float s1 = 0.0f;
        for (int k = 0; k < 256; ++k) s1 += m[k] * W0[k * 128 + t];
        s1 += beta * b0[t];
        out[g * 768 + 0 + half + t] = s1;
        h[t] = s1;
    }
    __syncthreads();
    float s2 = 0.0f;
    if (t < 128) {
        for (int k = 0; k < 128; ++k) s2 += h[k] * W1[k * 128 + t];
        s2 += beta * b1[t];
        out[g * 768 + 256 + half + t] = s2;
    }
    __syncthreads();
    if (t < 128) h[t] = s2;
    __syncthreads();
    if (t < 128) {
        float s3 = 0.0f;
        for (int k = 0; k < 128; ++k) s3 += h[k] * W2[k * 128 + t];
        s3 += beta * b2[t];
        out[g * 768 + 512 + half + t] = s3;
    }
}

extern "C" void kernel_launch(void* const* d_in, const int* in_sizes, int n_in,
                              void* d_out, int out_size, void* d_ws, size_t ws_size,
                              hipStream_t stream) {
    const float* x     = (const float*)d_in[0];
    const int*   ei    = (const int*)d_in[1];
    const int*   batch = (const int*)d_in[2];
    const float* W0    = (const float*)d_in[3];
    const float* b0    = (const float*)d_in[4];
    const float* W1    = (const float*)d_in[5];
    const float* b1    = (const float*)d_in[6];
    const float* W2    = (const float*)d_in[7];
    const float* b2    = (const float*)d_in[8];
    float* out = (float*)d_out;

    float*    ws     = (float*)d_ws;
    float*    Cdcol  = ws + CD_OFF;
    float*    deg    = ws + DEG_OFF;
    float*    counts = ws + CNT_OFF;
    float*    Y      = ws + Y_OFF;
    float*    part   = ws + PART_OFF;
    unsigned* bh     = (unsigned*)(ws + BH_OFF);
    unsigned* vals   = (unsigned*)(ws + VALS_OFF);

    bucket_g_k<<<NBG, 256, 0, stream>>>(ei, batch, vals, bh, Y);
    cd_col_k<<<N_GRAPHS, 1024, 0, stream>>>(vals, bh, batch, Cdcol, deg, counts);
    pool_k<<<NCHUNK * GSPLIT, 256, 0, stream>>>(x, batch, Cdcol, deg, Y, part);
    chain2_k<<<128, 256, 0, stream>>>(Y, part, counts, W0, b0, W1, b1, W2, b2, out);
}

// Round 9
// 127.663 us; speedup vs baseline: 1.2794x; 1.0136x over previous
//
#include <hip/hip_runtime.h>

#define N_NODES 20000
#define N_EDGES 640000
#define N_GRAPHS 64

// pool tiling
#define NCHUNK 128
#define CHUNK_SZ 157   // 128*157 = 20096 >= 20000
#define GSPLIT 8       // graph-dim split: 8 blocks of 8 graphs each
#define GSUB 8

// graph-bucket sort (fixed per-(block,g) segments; no cursor, no memset)
#define BG_TILE 2048
#define NBG 313        // ceil(640000/2048)
#define SEGCAP 80      // per-(block,g) slots: mean ~32, sigma ~5.7 (R7/R8-proven)
#define GR_CAP 768     // max nodes per graph: mean 312.5, sigma 17.5 -> 26 sigma
#define NSLOT4 (NBG * SEGCAP / 4)   // 6260 uint4 per graph

// ws layout (4B units), ws_size = 256 MiB:
//   Cdcol  [64][20000] f32     at 0          per-graph dst-count column
//   deg    [20000] f32         at 1,280,000
//   counts [64] f32            at 1,300,000
//   Y      [64][256] f32       at 1,300,064  (zeroed by bucket_g_k blk0; pool atomics)
//   part   [128][64][256] f32  at 1,316,448
//   bh     [313][64] u32       at 3,413,600
//   vals   [64][313][80] u32   at 3,433,632
#define CD_OFF      0
#define DEG_OFF     1280000
#define CNT_OFF     1300000
#define Y_OFF       1300064
#define PART_OFF    1316448
#define BH_OFF      3413600
#define VALS_OFF    3433632

// bucket edges by g = batch[src]: LDS rank + block prefix-sum, reorder tile in
// LDS by g, write vals in contiguous per-g runs (coalesced). Blk 0 zeroes Y.
__global__ __launch_bounds__(256) void bucket_g_k(const int* __restrict__ ei,
                                                  const int* __restrict__ batch,
                                                  unsigned* __restrict__ vals,
                                                  unsigned* __restrict__ bh,
                                                  float* __restrict__ Y) {
    __shared__ unsigned hist[N_GRAPHS];
    __shared__ unsigned base[N_GRAPHS + 1];
    __shared__ unsigned lv[BG_TILE];          // 8 KB reorder tile
    const int t = threadIdx.x;
    const int blk = blockIdx.x;
    if (t < N_GRAPHS) hist[t] = 0u;
    __syncthreads();

    const int e0 = blk * BG_TILE;
    const int ecnt = (e0 + BG_TILE <= N_EDGES) ? BG_TILE : (N_EDGES - e0);
    unsigned pv[8], rnk[8], gg[8];
#pragma unroll
    for (int k = 0; k < 8; ++k) {
        int i = t + k * 256;
        if (i < ecnt) {
            unsigned s = (unsigned)ei[e0 + i];
            unsigned d = (unsigned)ei[N_EDGES + e0 + i];
            unsigned g = (unsigned)batch[s];
            pv[k] = (s << 15) | d;
            gg[k] = g;
            rnk[k] = atomicAdd(&hist[g], 1u);
        } else {
            gg[k] = 0xFFFFFFFFu;
        }
    }
    __syncthreads();
    if (t == 0) {                              // exclusive scan over 64 counters
        unsigned acc = 0u;
        base[0] = 0u;
        for (int g = 0; g < N_GRAPHS; ++g) { acc += hist[g]; base[g + 1] = acc; }
    }
    if (t < N_GRAPHS) {
        unsigned c = hist[t];
        bh[blk * N_GRAPHS + t] = (c > SEGCAP) ? SEGCAP : c;
    }
    __syncthreads();
#pragma unroll
    for (int k = 0; k < 8; ++k) {
        if (gg[k] != 0xFFFFFFFFu) lv[base[gg[k]] + rnk[k]] = pv[k];
    }
    __syncthreads();
    // write out ordered tile: contiguous per-g runs -> coalesced global writes
    for (int i = t; i < ecnt; i += 256) {
        int lo = 0, hi = N_GRAPHS - 1;         // find g: base[g] <= i < base[g+1]
        while (lo < hi) { int m = (lo + hi + 1) >> 1; if (base[m] <= (unsigned)i) lo = m; else hi = m - 1; }
        unsigned slot = (unsigned)i - base[lo];
        if (slot < SEGCAP)
            vals[((size_t)lo * NBG + blk) * SEGCAP + slot] = lv[i];
    }
    if (blk == 0) {   // zero pool's atomic target (replaces memset dispatch)
        float4* y4 = (float4*)Y;
        for (int i = t; i < 64 * 64; i += 256) y4[i] = make_float4(0.f, 0.f, 0.f, 0.f);
    }
}

// block = (g, dst-quarter), 1024 threads (16 waves): u16 LDS hist over 5000
// nodes, vals read as coalesced uint4 (SEGCAP%4==0; seg via magic-mul).
// q==0 also builds deg over g's contiguous src range + counts[g].
__global__ __launch_bounds__(1024) void cd_col_k(const unsigned* __restrict__ vals,
                                                 const unsigned* __restrict__ bh,
                                                 const int* __restrict__ batch,
                                                 float* __restrict__ Cdcol,
                                                 float* __restrict__ deg,
                                                 float* __restrict__ counts) {
    __shared__ unsigned scnt[NBG];
    __shared__ unsigned dh[2500];          // 10 KB: 5000 dst counts, u16 halves
    __shared__ unsigned sdeg[GR_CAP];      // 3 KB (q==0 only)
    __shared__ int s_lo, s_hi;
    const int t = threadIdx.x;
    const int g = blockIdx.x >> 2;
    const int q = blockIdx.x & 3;
    const int d0 = q * 5000;

    for (int i = t; i < 2500; i += 1024) dh[i] = 0u;
    if (t < NBG) scnt[t] = bh[t * N_GRAPHS + g];
    if (q == 0) {
        if (t < GR_CAP) sdeg[t] = 0u;
        if (t == 0) {
            int lo = 0, hi = N_NODES;                    // lower_bound(g)
            while (lo < hi) { int m = (lo + hi) >> 1; if (batch[m] < g) lo = m + 1; else hi = m; }
            s_lo = lo;
            int lo2 = lo; hi = N_NODES;                  // lower_bound(g+1)
            while (lo2 < hi) { int m = (lo2 + hi) >> 1; if (batch[m] < g + 1) lo2 = m + 1; else hi = m; }
            s_hi = lo2;
        }
    }
    __syncthreads();
    const int lo = (q == 0) ? s_lo : 0;

    const uint4* v4 = (const uint4*)(vals + (size_t)g * NBG * SEGCAP);
    for (int i = t; i < NSLOT4; i += 1024) {
        uint4 v = *(v4 + i);
        unsigned w = (unsigned)i * 4u;
        unsigned seg = (unsigned)(((unsigned long long)w * 53687092ull) >> 32);  // w/80 exact
        unsigned local = w - seg * 80u;
        unsigned c = scnt[seg];
#define CD_ONE(VX, L)                                                            \
        if ((L) < c) {                                                           \
            int rd_ = (int)((VX) & 0x7FFFu) - d0;                                \
            if ((unsigned)rd_ < 5000u)                                           \
                atomicAdd(&dh[rd_ >> 1], 1u << ((rd_ & 1) * 16));                \
            if (q == 0) {                                                        \
                int rs_ = (int)((VX) >> 15) - lo;                                \
                if ((unsigned)rs_ < (unsigned)GR_CAP) atomicAdd(&sdeg[rs_], 1u); \
            }                                                                    \
        }
        CD_ONE(v.x, local + 0u)
        CD_ONE(v.y, local + 1u)
        CD_ONE(v.z, local + 2u)
        CD_ONE(v.w, local + 3u)
#undef CD_ONE
    }
    __syncthreads();

    float2* outc = (float2*)(Cdcol + (size_t)g * N_NODES + d0);
    for (int w = t; w < 2500; w += 1024) {
        unsigned v = dh[w];
        outc[w] = make_float2((float)(v & 0xFFFFu), (float)(v >> 16));
    }
    if (q == 0) {
        const int range = s_hi - lo;
        for (int i = t; i < range; i += 1024) deg[lo + i] = (float)sdeg[i];
        if (t == 0) {
            unsigned tot = 0;
            for (int i = 0; i < NBG; ++i) tot += scnt[i];
            counts[g] = (float)tot;
        }
    }
}

#define FMA8(C0, C1, XV)                                          \
    acc[0].x = fmaf(C0.x, XV.x, acc[0].x); acc[0].y = fmaf(C0.x, XV.y, acc[0].y); \
    acc[0].z = fmaf(C0.x, XV.z, acc[0].z); acc[0].w = fmaf(C0.x, XV.w, acc[0].w); \
    acc[1].x = fmaf(C0.y, XV.x, acc[1].x); acc[1].y = fmaf(C0.y, XV.y, acc[1].y); \
    acc[1].z = fmaf(C0.y, XV.z, acc[1].z); acc[1].w = fmaf(C0.y, XV.w, acc[1].w); \
    acc[2].x = fmaf(C0.z, XV.x, acc[2].x); acc[2].y = fmaf(C0.z, XV.y, acc[2].y); \
    acc[2].z = fmaf(C0.z, XV.z, acc[2].z); acc[2].w = fmaf(C0.z, XV.w, acc[2].w); \
    acc[3].x = fmaf(C0.w, XV.x, acc[3].x); acc[3].y = fmaf(C0.w, XV.y, acc[3].y); \
    acc[3].z = fmaf(C0.w, XV.z, acc[3].z); acc[3].w = fmaf(C0.w, XV.w, acc[3].w); \
    acc[4].x = fmaf(C1.x, XV.x, acc[4].x); acc[4].y = fmaf(C1.x, XV.y, acc[4].y); \
    acc[4].z = fmaf(C1.x, XV.z, acc[4].z); acc[4].w = fmaf(C1.x, XV.w, acc[4].w); \
    acc[5].x = fmaf(C1.y, XV.x, acc[5].x); acc[5].y = fmaf(C1.y, XV.y, acc[5].y); \
    acc[5].z = fmaf(C1.y, XV.z, acc[5].z); acc[5].w = fmaf(C1.y, XV.w, acc[5].w); \
    acc[6].x = fmaf(C1.z, XV.x, acc[6].x); acc[6].y = fmaf(C1.z, XV.y, acc[6].y); \
    acc[6].z = fmaf(C1.z, XV.z, acc[6].z); acc[6].w = fmaf(C1.z, XV.w, acc[6].w); \
    acc[7].x = fmaf(C1.w, XV.x, acc[7].x); acc[7].y = fmaf(C1.w, XV.y, acc[7].y); \
    acc[7].z = fmaf(C1.w, XV.z, acc[7].z); acc[7].w = fmaf(C1.w, XV.w, acc[7].w);

// pool: block = (chunk b, split j of 8 graphs). 4 waves = 4 node phases; node
// loop unrolled x4 with 4 independent x prefetches in flight; tree reduce.
__global__ __launch_bounds__(256) void pool_k(const float* __restrict__ x,
                                              const int* __restrict__ batch,
                                              const float* __restrict__ Cdcol,
                                              const float* __restrict__ deg,
                                              float* __restrict__ Y,
                                              float* __restrict__ part) {
    __shared__ float4 sc4[CHUNK_SZ * 2];      // 5 KB: [node][2] float4 (GSUB=8)
    __shared__ float sdeg[CHUNK_SZ];
    __shared__ int   sbatch[CHUNK_SZ];
    __shared__ float4 red[2 * GSUB * 64];     // 16 KB cross-phase reduce

    const int t = threadIdx.x;
    const int fg = t & 63;                    // float4 feature group
    const int p  = t >> 6;                    // phase == wave id
    const int b = blockIdx.x & 127;           // same chunk's 8 splits: same XCD mod 8
    const int j = blockIdx.x >> 7;
    const int n0 = b * CHUNK_SZ;
    const int cnt = (n0 + CHUNK_SZ <= N_NODES) ? CHUNK_SZ : (N_NODES - n0);

    // transpose-stage 8 Cd columns into [node][8] LDS layout
    float* sc = (float*)sc4;
    const float* cbase = Cdcol + (size_t)(j * GSUB) * N_NODES + n0;
#pragma unroll
    for (int k = 0; k < GSUB; ++k)
        for (int i = t; i < cnt; i += 256)
            sc[i * GSUB + k] = cbase[(size_t)k * N_NODES + i];
    if (j == 0) {
        for (int i = t; i < cnt; i += 256) {
            sdeg[i] = deg[n0 + i];
            sbatch[i] = batch[n0 + i];
        }
    }
    __syncthreads();

    const float4* xp = (const float4*)x + (size_t)n0 * 64 + fg;
#define XL(I) xp[(size_t)(I) * 64]
    float4 acc[GSUB];
#pragma unroll
    for (int k = 0; k < GSUB; ++k) acc[k] = make_float4(0.f, 0.f, 0.f, 0.f);

    if (j == 0) {
        // src pooling path (1/8 of blocks): prefetch-1 loop, wave-uniform flushes
        float4 accs = make_float4(0.f, 0.f, 0.f, 0.f);
        int gprev = (p < cnt) ? sbatch[p] : 0;
        int i = p;
        float4 xn = make_float4(0.f, 0.f, 0.f, 0.f);
        if (i < cnt) xn = XL(i);
        for (; i < cnt; i += 4) {
            float4 xv = xn;
            if (i + 4 < cnt) xn = XL(i + 4);
            int g = sbatch[i];                  // wave-uniform
            if (g != gprev) {                   // uniform branch
                float* yr = Y + gprev * 256 + fg * 4;
                atomicAdd(yr + 0, accs.x); atomicAdd(yr + 1, accs.y);
                atomicAdd(yr + 2, accs.z); atomicAdd(yr + 3, accs.w);
                accs = make_float4(0.f, 0.f, 0.f, 0.f);
                gprev = g;
            }
            float dg = sdeg[i];
            accs.x = fmaf(dg, xv.x, accs.x); accs.y = fmaf(dg, xv.y, accs.y);
            accs.z = fmaf(dg, xv.z, accs.z); accs.w = fmaf(dg, xv.w, accs.w);
            float4 c0 = sc4[i * 2], c1 = sc4[i * 2 + 1];
            FMA8(c0, c1, xv)
        }
        if (p < cnt) {
            float* yr = Y + gprev * 256 + fg * 4;
            atomicAdd(yr + 0, accs.x); atomicAdd(yr + 1, accs.y);
            atomicAdd(yr + 2, accs.z); atomicAdd(yr + 3, accs.w);
        }
    } else {
        // dst-only path: unroll x4, 4 loads in flight
        int i = p;
        float4 xa, xb, xc, xd;
        if (i      < cnt) xa = XL(i);
        if (i + 4  < cnt) xb = XL(i + 4);
        if (i + 8  < cnt) xc = XL(i + 8);
        if (i + 12 < cnt) xd = XL(i + 12);
        for (; i + 12 < cnt; i += 16) {
            float4 y0 = xa, y1 = xb, y2 = xc, y3 = xd;
            if (i + 16 < cnt) xa = XL(i + 16);
            if (i + 20 < cnt) xb = XL(i + 20);
            if (i + 24 < cnt) xc = XL(i + 24);
            if (i + 28 < cnt) xd = XL(i + 28);
            {
                float4 c0 = sc4[i * 2], c1 = sc4[i * 2 + 1];
                FMA8(c0, c1, y0)
            }
            {
                float4 c0 = sc4[(i + 4) * 2], c1 = sc4[(i + 4) * 2 + 1];
                FMA8(c0, c1, y1)
            }
            {
                float4 c0 = sc4[(i + 8) * 2], c1 = sc4[(i + 8) * 2 + 1];
                FMA8(c0, c1, y2)
            }
            {
                float4 c0 = sc4[(i + 12) * 2], c1 = sc4[(i + 12) * 2 + 1];
                FMA8(c0, c1, y3)
            }
        }
        for (; i < cnt; i += 4) {
            float4 xv = XL(i);
            float4 c0 = sc4[i * 2], c1 = sc4[i * 2 + 1];
            FMA8(c0, c1, xv)
        }
    }
#undef XL

    // cross-phase reduce 4 -> 2 -> 1 (lane-consecutive, conflict-free)
    if (p >= 2) {
#pragma unroll
        for (int k = 0; k < GSUB; ++k) red[(p - 2) * (GSUB * 64) + k * 64 + fg] = acc[k];
    }
    __syncthreads();
    if (p < 2) {
#pragma unroll
        for (int k = 0; k < GSUB; ++k) {
            float4 v = red[p * (GSUB * 64) + k * 64 + fg];
            acc[k].x += v.x; acc[k].y += v.y; acc[k].z += v.z; acc[k].w += v.w;
        }
    }
    __syncthreads();
    if (p == 1) {
#pragma unroll
        for (int k = 0; k < GSUB; ++k) red[k * 64 + fg] = acc[k];
    }
    __syncthreads();
    if (p == 0) {
        float4* part4 = (float4*)part;
#pragma unroll
        for (int k = 0; k < GSUB; ++k) {
            float4 v = red[k * 64 + fg];
            acc[k].x += v.x; acc[k].y += v.y; acc[k].z += v.z; acc[k].w += v.w;
            part4[(size_t)(b * 64 + j * GSUB + k) * 64 + fg] = acc[k];
        }
    }
}

// fused reduce + chain: 128 blocks x 256 threads. Dst-row blocks (r>=64)
// reduce their 128 part slabs directly; Y rows 64..127 never materialized.
__global__ __launch_bounds__(256) void chain2_k(const float* __restrict__ Y,
                                                const float* __restrict__ part,
                                                const float* __restrict__ counts,
                                                const float* __restrict__ W0, const float* __restrict__ b0,
                                                const float* __restrict__ W1, const float* __restrict__ b1,
                                                const float* __restrict__ W2, const float* __restrict__ b2,
                                                float* __restrict__ out) {
    __shared__ float m[256];
    __shared__ float h[128];
    const int r = blockIdx.x;
    const int t = threadIdx.x;
    const int g = r & 63;
    const int half = (r >= 64) ? 128 : 0;

    float c = counts[g];
    float inv = 1.0f / fmaxf(c, 1.0f);
    float beta = c * inv;

    if (r < 64) {
        m[t] = Y[r * 256 + t] * inv;
    } else {
        float s = 0.0f;
        for (int bb = 0; bb < NCHUNK; ++bb) s += part[(size_t)(bb * 64 + g) * 256 + t];
        m[t] = s * inv;
    }
    __syncthreads();

    if (t < 128) {
        float s1 = 0.0f;
        for (int k = 0; k < 256; ++k) s1 += m[k] * W0[k * 128 + t];
        s1 += beta * b0[t];
        out[g * 768 + 0 + half + t] = s1;
        h[t] = s1;
    }
    __syncthreads();
    float s2 = 0.0f;
    if (t < 128) {
        for (int k = 0; k < 128; ++k) s2 += h[k] * W1[k * 128 + t];
        s2 += beta * b1[t];
        out[g * 768 + 256 + half + t] = s2;
    }
    __syncthreads();
    if (t < 128) h[t] = s2;
    __syncthreads();
    if (t < 128) {
        float s3 = 0.0f;
        for (int k = 0; k < 128; ++k) s3 += h[k] * W2[k * 128 + t];
        s3 += beta * b2[t];
        out[g * 768 + 512 + half + t] = s3;
    }
}

extern "C" void kernel_launch(void* const* d_in, const int* in_sizes, int n_in,
                              void* d_out, int out_size, void* d_ws, size_t ws_size,
                              hipStream_t stream) {
    const float* x     = (const float*)d_in[0];
    const int*   ei    = (const int*)d_in[1];
    const int*   batch = (const int*)d_in[2];
    const float* W0    = (const float*)d_in[3];
    const float* b0    = (const float*)d_in[4];
    const float* W1    = (const float*)d_in[5];
    const float* b1    = (const float*)d_in[6];
    const float* W2    = (const float*)d_in[7];
    const float* b2    = (const float*)d_in[8];
    float* out = (float*)d_out;

    float*    ws     = (float*)d_ws;
    float*    Cdcol  = ws + CD_OFF;
    float*    deg    = ws + DEG_OFF;
    float*    counts = ws + CNT_OFF;
    float*    Y      = ws + Y_OFF;
    float*    part   = ws + PART_OFF;
    unsigned* bh     = (unsigned*)(ws + BH_OFF);
    unsigned* vals   = (unsigned*)(ws + VALS_OFF);

    bucket_g_k<<<NBG, 256, 0, stream>>>(ei, batch, vals, bh, Y);
    cd_col_k<<<N_GRAPHS * 4, 1024, 0, stream>>>(vals, bh, batch, Cdcol, deg, counts);
    pool_k<<<NCHUNK * GSPLIT, 256, 0, stream>>>(x, batch, Cdcol, deg, Y, part);
    chain2_k<<<128, 256, 0, stream>>>(Y, part, counts, W0, b0, W1, b1, W2, b2, out);
}